// Round 3
// baseline (81.255 us; speedup 1.0000x reference)
//
#include <hip/hip_runtime.h>
#include <hip/hip_bf16.h>

// Problem: B=256, N=16384, D=7, NUM_CLASSES=3, EPS=1e-6
// Inputs (float32): output [B,N,7], target [B,N,7]. Output: scalar float32.
//
// Single fused kernel: grid-strided tiles with T14 register-prefetch staging
// (issue next tile's global loads into VGPRs before computing current tile),
// per-block reduce -> partials in d_ws, last-finished block does the final
// reduction (agent-scope atomics for cross-XCD visibility).

#define RD 7
#define NRECTOT (256 * 16384)            // 4,194,304 records
#define BLOCK 256
#define GRID 2048
#define ITERS (NRECTOT / (GRID * BLOCK)) // 8
#define STEP (GRID * BLOCK)
#define F4T ((BLOCK * RD) / 4)           // 448 float4 per tensor per tile

__global__ __launch_bounds__(BLOCK) void loss_kernel(
    const float* __restrict__ out, const float* __restrict__ tgt,
    float* __restrict__ partial, unsigned int* __restrict__ counter,
    float* __restrict__ result) {
    __shared__ float4 so4[F4T];
    __shared__ float4 st4[F4T];
    const float* so = (const float*)so4;
    const float* st = (const float*)st4;
    const float4* og = (const float4*)out;
    const float4* tg = (const float4*)tgt;

    const int t = threadIdx.x;
    const bool second = (t < F4T - BLOCK);  // threads 0..191 (wave-uniform: waves 0-2)

    float acc = 0.0f;
    int base = blockIdx.x * BLOCK;

    // Prologue: tile 0 into registers.
    int g4 = (base * RD) >> 2;              // base*7 is divisible by 4 (1792/rec-tile)
    float4 ro0 = og[g4 + t], rt0 = tg[g4 + t];
    float4 ro1{}, rt1{};
    if (second) { ro1 = og[g4 + BLOCK + t]; rt1 = tg[g4 + BLOCK + t]; }

#pragma unroll
    for (int i = 0; i < ITERS; ++i) {
        // T14 issue-early: next tile's loads start before current compute.
        float4 no0{}, nt0{}, no1{}, nt1{};
        if (i + 1 < ITERS) {
            const int ng4 = ((base + STEP) * RD) >> 2;
            no0 = og[ng4 + t]; nt0 = tg[ng4 + t];
            if (second) { no1 = og[ng4 + BLOCK + t]; nt1 = tg[ng4 + BLOCK + t]; }
        }
        __syncthreads();  // previous tile's LDS readers done
        so4[t] = ro0; st4[t] = rt0;
        if (second) { so4[BLOCK + t] = ro1; st4[BLOCK + t] = rt1; }
        __syncthreads();  // tile visible

        // One record per thread. Stride-7 LDS: gcd(7,32)=1 -> conflict-free
        // within 32 lanes; the 2-way 64-lane aliasing is free (m136).
        const float* ro = &so[t * RD];
        const float* rt = &st[t * RD];

        const float p_obj = ro[0];
        const float px = ro[1], py = ro[2], ps = ro[3];
        const float l0 = ro[4], l1 = ro[5], l2 = ro[6];
        const float t_obj = rt[0];
        const float tx = rt[1], ty = rt[2], ts = rt[3];
        const float cls = rt[4];

        const float m = (t_obj > 0.5f) ? 1.0f : 0.0f;

        // box regression
        const float dx = tx - px, dy = ty - py;
        const float dsz = __fsqrt_rn(ts) - __fsqrt_rn(ps);
        const float box = dx * dx + dy * dy + 2.0f * dsz * dsz;

        // IoU of axis-aligned squares
        const float hp = 0.5f * ps, ht = 0.5f * ts;
        const float lx = fmaxf(px - hp, tx - ht);
        const float rx = fminf(px + hp, tx + ht);
        const float ly = fmaxf(py - hp, ty - ht);
        const float ry = fminf(py + hp, ty + ht);
        const float inter = fmaxf(rx - lx, 0.0f) * fmaxf(ry - ly, 0.0f);
        const float uni = ps * ps + ts * ts - inter;
        const float iou = inter / (uni + 1e-6f);

        // shared log terms (p_obj in (0.01,0.99))
        const float logp  = __logf(p_obj);
        const float log1p = __logf(1.0f - p_obj);

        const float bce_obj = -(iou * logp + (1.0f - iou) * log1p);

        // 3-class log-softmax CE
        const float mx = fmaxf(fmaxf(l0, l1), l2);
        const float esum = __expf(l0 - mx) + __expf(l1 - mx) + __expf(l2 - mx);
        const float lse = mx + __logf(esum);
        const float lcls = (cls < 0.5f) ? l0 : ((cls < 1.5f) ? l1 : l2);
        const float ce = lse - lcls;

        const float bce_noobj = -(t_obj * logp + (1.0f - t_obj) * log1p);

        acc += m * (5.0f * box + 2.0f * ce + bce_obj)
             + 1.5f * (1.0f - m) * bce_noobj;

        // rotate prefetched registers
        ro0 = no0; rt0 = nt0; ro1 = no1; rt1 = nt1;
        base += STEP;
    }

    // block reduce
#pragma unroll
    for (int off = 32; off > 0; off >>= 1) acc += __shfl_down(acc, off);
    __shared__ float wsum[BLOCK / 64];
    __shared__ bool amLast;
    if ((t & 63) == 0) wsum[t >> 6] = acc;
    __syncthreads();
    if (t == 0) {
        float s = wsum[0] + wsum[1] + wsum[2] + wsum[3];
        // publish partial at agent (device) scope, then count completion
        __hip_atomic_store(&partial[blockIdx.x], s, __ATOMIC_RELAXED,
                           __HIP_MEMORY_SCOPE_AGENT);
        unsigned int old = __hip_atomic_fetch_add(counter, 1u, __ATOMIC_ACQ_REL,
                                                  __HIP_MEMORY_SCOPE_AGENT);
        amLast = (old == GRID - 1);
    }
    __syncthreads();
    if (amLast) {
        // last-finished block: parallel final reduce of GRID partials
        float a = 0.0f;
#pragma unroll
        for (int k = 0; k < GRID / BLOCK; ++k)
            a += __hip_atomic_load(&partial[k * BLOCK + t], __ATOMIC_RELAXED,
                                   __HIP_MEMORY_SCOPE_AGENT);
#pragma unroll
        for (int off = 32; off > 0; off >>= 1) a += __shfl_down(a, off);
        if ((t & 63) == 0) wsum[t >> 6] = a;
        __syncthreads();
        if (t == 0) result[0] = wsum[0] + wsum[1] + wsum[2] + wsum[3];
    }
}

extern "C" void kernel_launch(void* const* d_in, const int* in_sizes, int n_in,
                              void* d_out, int out_size, void* d_ws, size_t ws_size,
                              hipStream_t stream) {
    const float* out = (const float*)d_in[0];  // output [B,N,7]
    const float* tgt = (const float*)d_in[1];  // target [B,N,7]
    float* result = (float*)d_out;

    // d_ws layout: [0..3] counter, [256..] partials (GRID floats)
    unsigned int* counter = (unsigned int*)d_ws;
    float* partial = (float*)((char*)d_ws + 256);

    // zero the completion counter every call (ws is NOT re-poisoned between
    // replays; kernel leaves counter==GRID, so reset in-stream -- graph-legal)
    hipMemsetAsync(counter, 0, sizeof(unsigned int), stream);

    loss_kernel<<<GRID, BLOCK, 0, stream>>>(out, tgt, partial, counter, result);
}

// Round 4
// 44.854 us; speedup vs baseline: 1.8116x; 1.8116x over previous
//
#include <hip/hip_runtime.h>
#include <hip/hip_bf16.h>

// Problem: B=256, N=16384, D=7, NUM_CLASSES=3, EPS=1e-6
// Inputs (float32): output [B,N,7], target [B,N,7]. Output: scalar float32.
//
// No-LDS design: each thread owns 4 consecutive records = 28 floats = 112 B
// = 7 aligned float4 loads per tensor. All array indexing is compile-time
// static so everything lives in VGPRs. No barriers in the hot path -> memory
// latency hidden by per-thread ILP (14 loads in flight) + TLP.

#define RD 7
#define NRECTOT (256 * 16384)            // 4,194,304 records
#define BLOCK 256
#define RPT 4                            // records per thread
#define NTHREADS (NRECTOT / RPT)         // 1,048,576
#define GRID (NTHREADS / BLOCK)          // 4096 blocks, one-shot

__device__ __forceinline__ float record_loss(const float* ro, const float* rt) {
    const float p_obj = ro[0];
    const float px = ro[1], py = ro[2], ps = ro[3];
    const float l0 = ro[4], l1 = ro[5], l2 = ro[6];
    const float t_obj = rt[0];
    const float tx = rt[1], ty = rt[2], ts = rt[3];
    const float cls = rt[4];

    const float m = (t_obj > 0.5f) ? 1.0f : 0.0f;

    // box regression
    const float dx = tx - px, dy = ty - py;
    const float dsz = __fsqrt_rn(ts) - __fsqrt_rn(ps);
    const float box = dx * dx + dy * dy + 2.0f * dsz * dsz;

    // IoU of axis-aligned squares
    const float hp = 0.5f * ps, ht = 0.5f * ts;
    const float lx = fmaxf(px - hp, tx - ht);
    const float rx = fminf(px + hp, tx + ht);
    const float ly = fmaxf(py - hp, ty - ht);
    const float ry = fminf(py + hp, ty + ht);
    const float inter = fmaxf(rx - lx, 0.0f) * fmaxf(ry - ly, 0.0f);
    const float uni = ps * ps + ts * ts - inter;
    const float iou = inter / (uni + 1e-6f);

    // shared log terms (p_obj in (0.01,0.99))
    const float logp  = __logf(p_obj);
    const float log1p = __logf(1.0f - p_obj);

    const float bce_obj = -(iou * logp + (1.0f - iou) * log1p);

    // 3-class log-softmax CE
    const float mx = fmaxf(fmaxf(l0, l1), l2);
    const float esum = __expf(l0 - mx) + __expf(l1 - mx) + __expf(l2 - mx);
    const float lse = mx + __logf(esum);
    const float lcls = (cls < 0.5f) ? l0 : ((cls < 1.5f) ? l1 : l2);
    const float ce = lse - lcls;

    const float bce_noobj = -(t_obj * logp + (1.0f - t_obj) * log1p);

    return m * (5.0f * box + 2.0f * ce + bce_obj)
         + 1.5f * (1.0f - m) * bce_noobj;
}

__global__ __launch_bounds__(BLOCK) void loss_partial_kernel(
    const float* __restrict__ out, const float* __restrict__ tgt,
    float* __restrict__ partial) {
    const int t = threadIdx.x;
    const int tid = blockIdx.x * BLOCK + t;      // 0 .. NTHREADS-1

    // Thread's 4 records start at float offset tid*28 (= tid*7 float4s, 16B aligned).
    const float4* og = (const float4*)out + (size_t)tid * RD;
    const float4* tg = (const float4*)tgt + (size_t)tid * RD;

    // Load 28 floats per tensor into registers (static indices only).
    float vo[RPT * RD], vt[RPT * RD];
#pragma unroll
    for (int k = 0; k < RD; ++k) {
        *(float4*)&vo[4 * k] = og[k];
        *(float4*)&vt[4 * k] = tg[k];
    }

    float acc = 0.0f;
#pragma unroll
    for (int j = 0; j < RPT; ++j)
        acc += record_loss(&vo[j * RD], &vt[j * RD]);

    // wave reduce (64 lanes)
#pragma unroll
    for (int off = 32; off > 0; off >>= 1) acc += __shfl_down(acc, off);

    __shared__ float wsum[BLOCK / 64];
    if ((t & 63) == 0) wsum[t >> 6] = acc;
    __syncthreads();
    if (t == 0)
        partial[blockIdx.x] = wsum[0] + wsum[1] + wsum[2] + wsum[3];
}

__global__ __launch_bounds__(BLOCK) void reduce_final_kernel(
    const float* __restrict__ partial, float* __restrict__ outp, int n) {
    float a = 0.0f;
    for (int i = threadIdx.x; i < n; i += BLOCK) a += partial[i];
#pragma unroll
    for (int off = 32; off > 0; off >>= 1) a += __shfl_down(a, off);
    __shared__ float wsum[BLOCK / 64];
    if ((threadIdx.x & 63) == 0) wsum[threadIdx.x >> 6] = a;
    __syncthreads();
    if (threadIdx.x == 0)
        outp[0] = wsum[0] + wsum[1] + wsum[2] + wsum[3];
}

extern "C" void kernel_launch(void* const* d_in, const int* in_sizes, int n_in,
                              void* d_out, int out_size, void* d_ws, size_t ws_size,
                              hipStream_t stream) {
    const float* out = (const float*)d_in[0];  // output [B,N,7]
    const float* tgt = (const float*)d_in[1];  // target [B,N,7]
    float* partial = (float*)d_ws;             // GRID floats of scratch (16 KB)
    float* result = (float*)d_out;

    loss_partial_kernel<<<GRID, BLOCK, 0, stream>>>(out, tgt, partial);
    reduce_final_kernel<<<1, BLOCK, 0, stream>>>(partial, result, GRID);
}